// Round 4
// baseline (147.024 us; speedup 1.0000x reference)
//
#include <hip/hip_runtime.h>

// PointSIFT: octant-wise nearest neighbor within radius + group.
// B=2, N=4096, C=64 fixed by the problem.
// Two-kernel split-candidate design:
//   kernel A: 1024 blocks, each stages HALF the candidates (32KB LDS ->
//             4 blocks/CU, 4 waves/SIMD) and writes partial per-octant
//             (dist, idx) scoreboards into the out1 region (overwritten later).
//   kernel B: merges the two partials per (b,n,octant) and does the gather.
#define BB 2
#define NN 4096
#define CC 64
#define QPB 16              // queries per block
#define TPQ 16              // threads per query (one candidate stripe each)
#define NT (QPB * TPQ)      // 256 threads per block
#define HALVES 2
#define NPH (NN / HALVES)   // 2048 candidates per block
#define BIGF 1e10f

// flat output layout (all float32):
//   out0 grouped_xyz   [B,N,8,3]
//   out1 grouped_points[B,N,8,67]
//   out2 idx (as float)[B,N,8]
#define OUT0_OFF 0
#define OUT1_OFF (BB * NN * 8 * 3)               /* 196608 */
#define OUT2_OFF (OUT1_OFF + BB * NN * 8 * 67)   /* 4587520 */

__global__ __launch_bounds__(NT, 4) void pointsift_select(
    const float* __restrict__ xyz, const float* __restrict__ radius_p,
    float* __restrict__ out)
{
    __shared__ float s_xyz4[NPH * 4];         // 32 KiB: this half's coords

    const int tid = threadIdx.x;
    const int groups_per_batch = NN / QPB;    // 256
    int blk = blockIdx.x;
    const int h = blk & (HALVES - 1);         // candidate half
    blk >>= 1;
    const int b = blk / groups_per_batch;
    const int qbase = (blk % groups_per_batch) * QPB;

    const float* srcb = xyz + (size_t)b * NN * 3;
    // stage this half's candidates into LDS, padded to float4 stride
    {
        const float* src = srcb + (size_t)h * NPH * 3;
        for (int p = tid; p < NPH; p += NT) {
            float x = src[p * 3 + 0];
            float y = src[p * 3 + 1];
            float z = src[p * 3 + 2];
            float4* d = (float4*)(s_xyz4 + p * 4);
            *d = make_float4(x, y, z, 0.0f);
        }
    }

    const float r = radius_p[0];
    const float judge = __fmul_rn(r, r);

    const int n = qbase + (tid >> 4);         // query index within batch
    const int sub = tid & (TPQ - 1);          // candidate stripe id

    // query coords from global (query may live in either half); L2-hot
    const float qx = srcb[n * 3 + 0];
    const float qy = srcb[n * 3 + 1];
    const float qz = srcb[n * 3 + 2];

    __syncthreads();

    // register scoreboard, seeded with the diagonal entry (judge, n).
    // Seed lives in BOTH halves; merge tie-break handles the duplicate.
    float bd[8]; int bi[8];
    #pragma unroll
    for (int o = 0; o < 8; ++o) { bd[o] = judge; bi[o] = n; }

    const int pg0 = h * NPH;                  // global index of local p=0
    const float4* sx4 = (const float4*)s_xyz4;
    #pragma unroll 8
    for (int p = sub; p < NPH; p += TPQ) {
        float4 c = sx4[p];
        // diff = candidate - query, fp32, no contraction (must match numpy ref)
        float dx = __fsub_rn(c.x, qx);
        float dy = __fsub_rn(c.y, qy);
        float dz = __fsub_rn(c.z, qz);
        float dist = __fadd_rn(__fadd_rn(__fmul_rn(dx, dx), __fmul_rn(dy, dy)),
                               __fmul_rn(dz, dz));
        // octant code: truncation of (diff + 1.0f), dotted with [4,2,1]
        int code = ((int)__fadd_rn(dx, 1.0f)) * 4 +
                   ((int)__fadd_rn(dy, 1.0f)) * 2 +
                   ((int)__fadd_rn(dz, 1.0f));
        // dist<judge is subsumed by dist<bd[o] (bd[o] <= judge always)
        float dv = (dist > 1e-10f) ? dist : BIGF;
        int pg = pg0 + p;
        #pragma unroll
        for (int o = 0; o < 8; ++o) {
            bool m = (code == o) & (dv < bd[o]);
            bd[o] = m ? dv : bd[o];
            bi[o] = m ? pg : bi[o];
        }
    }

    // butterfly reduce over the 16 stripe-threads of this query
    // (lanes are 16-aligned within the wave); tie-break: smaller index wins
    #pragma unroll
    for (int m = 1; m < TPQ; m <<= 1) {
        #pragma unroll
        for (int o = 0; o < 8; ++o) {
            float od = __shfl_xor(bd[o], m, 64);
            int   oi = __shfl_xor(bi[o], m, 64);
            if (od < bd[o] || (od == bd[o] && oi < bi[o])) {
                bd[o] = od; bi[o] = oi;
            }
        }
    }

    // stripe-leader writes this half's 8 partial (dist, idx) pairs into the
    // out1 scratch area: tuple t = (b*N+n)*8+o gets floats [t*67+2h, t*67+2h+1]
    if (sub == 0) {
        const size_t tb = ((size_t)b * NN + n) * 8;
        #pragma unroll
        for (int o = 0; o < 8; ++o) {
            size_t base = OUT1_OFF + (tb + o) * 67 + 2 * h;
            out[base + 0] = bd[o];
            out[base + 1] = (float)bi[o];   // idx < 4096: exact in fp32
        }
    }
}

__global__ __launch_bounds__(NT) void pointsift_reduce_gather(
    const float* __restrict__ xyz, const float* __restrict__ points,
    float* __restrict__ out)
{
    __shared__ int s_sel[NT];

    const int tid = threadIdx.x;
    const int t = blockIdx.x * NT + tid;      // tuple id = (b*N+n)*8 + o
    // read this tuple's two partials (written by kernel A)
    const float* part = out + OUT1_OFF + (size_t)t * 67;
    float d0 = part[0]; int i0 = (int)part[1];
    float d1 = part[2]; int i1 = (int)part[3];
    // first-min merge; half-0 indices < half-1 indices, seed dups are equal
    bool take1 = (d1 < d0) || ((d1 == d0) & (i1 < i0));
    int sel = take1 ? i1 : i0;
    out[OUT2_OFF + t] = (float)sel;           // idx as float
    s_sel[tid] = sel;
    __syncthreads();                          // all partial reads done before
                                              // gather overwrites out1 below

    // gather: wave per (query,octant) tuple; lane c handles channel c.
    const int wave = tid >> 6;
    const int lane = tid & 63;
    for (int pid = wave; pid < NT; pid += NT / 64) {
        const int tt = blockIdx.x * NT + pid;
        const int bn = tt >> 3;               // b*N + n
        const int b = bn >> 12;
        const int n = bn & (NN - 1);
        const int i = s_sel[pid];
        const float* xb = xyz + (size_t)b * NN * 3;
        const size_t rest = (size_t)tt;
        float f = points[((size_t)b * NN + i) * CC + lane];
        out[OUT1_OFF + rest * 67 + 3 + lane] = f;
        if (lane < 3) {
            float g = __fsub_rn(xb[i * 3 + lane], xb[n * 3 + lane]);
            out[OUT0_OFF + rest * 3 + lane] = g;
            out[OUT1_OFF + rest * 67 + lane] = g;
        }
    }
}

extern "C" void kernel_launch(void* const* d_in, const int* in_sizes, int n_in,
                              void* d_out, int out_size, void* d_ws, size_t ws_size,
                              hipStream_t stream) {
    const float* xyz    = (const float*)d_in[0];
    const float* points = (const float*)d_in[1];
    const float* radius = (const float*)d_in[2];
    float* out = (float*)d_out;

    // kernel A: partial octant select per candidate-half
    hipLaunchKernelGGL(pointsift_select,
                       dim3(BB * (NN / QPB) * HALVES), dim3(NT), 0, stream,
                       xyz, radius, out);
    // kernel B: merge partials + gather
    hipLaunchKernelGGL(pointsift_reduce_gather,
                       dim3(BB * NN * 8 / NT), dim3(NT), 0, stream,
                       xyz, points, out);
}

// Round 5
// 138.684 us; speedup vs baseline: 1.0601x; 1.0601x over previous
//
#include <hip/hip_runtime.h>

// PointSIFT: octant-wise nearest neighbor within radius + group.
// B=2, N=4096, C=64 fixed by the problem.
// Three-kernel design:
//   A select: 2048 blocks, each stages a QUARTER of the candidates (16KB LDS
//             -> 8 blocks/CU, 8 waves/SIMD) and writes partial per-octant
//             (dist, idx) pairs into the out1 region (scratch, overwritten).
//   B merge:  first-min across the 4 partials -> out2 (idx).
//   C gather: one thread per output element, fully independent.
#define BB 2
#define NN 4096
#define CC 64
#define QPB 16              // queries per block
#define TPQ 16              // threads per query (one candidate stripe each)
#define NT (QPB * TPQ)      // 256 threads per block
#define QUARTERS 4
#define NPQ (NN / QUARTERS) // 1024 candidates per select block
#define BIGF 1e10f

// flat output layout (all float32):
//   out0 grouped_xyz   [B,N,8,3]
//   out1 grouped_points[B,N,8,67]
//   out2 idx (as float)[B,N,8]
#define OUT0_OFF 0
#define OUT1_OFF (BB * NN * 8 * 3)               /* 196608 */
#define OUT2_OFF (OUT1_OFF + BB * NN * 8 * 67)   /* 4587520 */

__global__ __launch_bounds__(NT, 8) void pointsift_select(
    const float* __restrict__ xyz, const float* __restrict__ radius_p,
    float* __restrict__ out)
{
    __shared__ float s_xyz4[NPQ * 4];         // 16 KiB: this quarter's coords

    const int tid = threadIdx.x;
    const int groups_per_batch = NN / QPB;    // 256
    int blk = blockIdx.x;
    const int h = blk & (QUARTERS - 1);       // candidate quarter
    blk >>= 2;
    const int b = blk / groups_per_batch;
    const int qbase = (blk % groups_per_batch) * QPB;

    const float* srcb = xyz + (size_t)b * NN * 3;
    // stage this quarter's candidates into LDS, padded to float4 stride
    {
        const float* src = srcb + (size_t)h * NPQ * 3;
        for (int p = tid; p < NPQ; p += NT) {
            float4* d = (float4*)(s_xyz4 + p * 4);
            *d = make_float4(src[p * 3 + 0], src[p * 3 + 1], src[p * 3 + 2], 0.0f);
        }
    }

    const float r = radius_p[0];
    const float judge = __fmul_rn(r, r);

    const int n = qbase + (tid >> 4);         // query index within batch
    const int sub = tid & (TPQ - 1);          // candidate stripe id

    // query coords from global (query may live in any quarter); L2-hot
    const float qx = srcb[n * 3 + 0];
    const float qy = srcb[n * 3 + 1];
    const float qz = srcb[n * 3 + 2];

    __syncthreads();

    // register scoreboard, seeded with the diagonal entry (judge, n).
    // Seed appears in all quarters; merge tie-break handles duplicates.
    float bd[8]; int bi[8];
    #pragma unroll
    for (int o = 0; o < 8; ++o) { bd[o] = judge; bi[o] = n; }

    const int pg0 = h * NPQ;                  // global index of local p=0
    const float4* sx4 = (const float4*)s_xyz4;
    #pragma unroll 4
    for (int p = sub; p < NPQ; p += TPQ) {
        float4 c = sx4[p];
        // diff = candidate - query, fp32, no contraction (must match numpy ref)
        float dx = __fsub_rn(c.x, qx);
        float dy = __fsub_rn(c.y, qy);
        float dz = __fsub_rn(c.z, qz);
        float dist = __fadd_rn(__fadd_rn(__fmul_rn(dx, dx), __fmul_rn(dy, dy)),
                               __fmul_rn(dz, dz));
        // octant code: truncation of (diff + 1.0f), dotted with [4,2,1];
        // xyz in [0,1) -> each bit is 0/1, code in [0,7]
        int code = ((int)__fadd_rn(dx, 1.0f)) * 4 +
                   ((int)__fadd_rn(dy, 1.0f)) * 2 +
                   ((int)__fadd_rn(dz, 1.0f));
        // dist<judge is subsumed by dist<bd[o] (bd[o] <= judge always)
        float dv = (dist > 1e-10f) ? dist : BIGF;
        int pg = pg0 + p;
        #pragma unroll
        for (int o = 0; o < 8; ++o) {
            float cand = (code == o) ? dv : BIGF;   // cmp + cndmask
            bool m = cand < bd[o];                  // v_cmp
            bd[o] = fminf(cand, bd[o]);             // v_min_f32
            bi[o] = m ? pg : bi[o];                 // v_cndmask
        }
    }

    // butterfly reduce over the 16 stripe-threads of this query
    // (lanes are 16-aligned within the wave); tie-break: smaller index wins
    #pragma unroll
    for (int m = 1; m < TPQ; m <<= 1) {
        #pragma unroll
        for (int o = 0; o < 8; ++o) {
            float od = __shfl_xor(bd[o], m, 64);
            int   oi = __shfl_xor(bi[o], m, 64);
            if (od < bd[o] || (od == bd[o] && oi < bi[o])) {
                bd[o] = od; bi[o] = oi;
            }
        }
    }

    // stripe-leader writes this quarter's 8 partial (dist, idx) pairs into
    // the out1 scratch area: tuple t=(b*N+n)*8+o gets floats t*67+2h, +2h+1
    if (sub == 0) {
        const size_t tb = ((size_t)b * NN + n) * 8;
        #pragma unroll
        for (int o = 0; o < 8; ++o) {
            size_t base = OUT1_OFF + (tb + o) * 67 + 2 * h;
            out[base + 0] = bd[o];
            out[base + 1] = (float)bi[o];   // idx < 4096: exact in fp32
        }
    }
}

// merge the 4 quarter-partials per tuple -> out2 (selected idx, as float)
__global__ __launch_bounds__(256) void pointsift_merge(float* __restrict__ out)
{
    const int t = blockIdx.x * 256 + threadIdx.x;   // tuple id
    const float* part = out + OUT1_OFF + (size_t)t * 67;
    float bd = part[0]; int bi = (int)part[1];
    #pragma unroll
    for (int h = 1; h < QUARTERS; ++h) {
        float d = part[2 * h]; int i = (int)part[2 * h + 1];
        if (d < bd || (d == bd && i < bi)) { bd = d; bi = i; }
    }
    out[OUT2_OFF + t] = (float)bi;
}

// one thread per output element: item = tuple*70 + j
//   j in [0,67): out1[t*67+j]  (j<3: grouped_xyz channel, else feature j-3)
//   j in [67,70): out0[t*3 + (j-67)]
__global__ __launch_bounds__(256) void pointsift_gather(
    const float* __restrict__ xyz, const float* __restrict__ points,
    float* __restrict__ out)
{
    const unsigned item = blockIdx.x * 256u + threadIdx.x;   // grid is exact
    const unsigned t = item / 70u;
    const unsigned j = item - t * 70u;
    const unsigned bn = t >> 3;               // b*N + n
    const unsigned b = bn >> 12;
    const unsigned n = bn & (NN - 1);
    const int i = (int)out[OUT2_OFF + t];     // merged idx (broadcast read)
    const float* xb = xyz + (size_t)b * NN * 3;
    if (j < 67u) {
        float v;
        if (j < 3u) v = __fsub_rn(xb[i * 3 + j], xb[n * 3 + j]);
        else        v = points[((size_t)b * NN + i) * CC + (j - 3u)];
        out[OUT1_OFF + (size_t)t * 67 + j] = v;
    } else {
        const unsigned c = j - 67u;
        out[OUT0_OFF + (size_t)t * 3 + c] =
            __fsub_rn(xb[i * 3 + c], xb[n * 3 + c]);
    }
}

extern "C" void kernel_launch(void* const* d_in, const int* in_sizes, int n_in,
                              void* d_out, int out_size, void* d_ws, size_t ws_size,
                              hipStream_t stream) {
    const float* xyz    = (const float*)d_in[0];
    const float* points = (const float*)d_in[1];
    const float* radius = (const float*)d_in[2];
    float* out = (float*)d_out;

    // A: partial octant select per candidate-quarter (2048 blocks)
    hipLaunchKernelGGL(pointsift_select,
                       dim3(BB * (NN / QPB) * QUARTERS), dim3(NT), 0, stream,
                       xyz, radius, out);
    // B: merge partials -> out2 (16384 tuples / 256 = 64 blocks)
    hipLaunchKernelGGL(pointsift_merge,
                       dim3(BB * NN * 8 / 256), dim3(256), 0, stream, out);
    // C: gather, one thread per element (16384*70/256 = 4480 blocks, exact)
    hipLaunchKernelGGL(pointsift_gather,
                       dim3(BB * NN * 8 * 70 / 256), dim3(256), 0, stream,
                       xyz, points, out);
}

// Round 6
// 117.373 us; speedup vs baseline: 1.2526x; 1.1816x over previous
//
#include <hip/hip_runtime.h>

// PointSIFT: octant-wise nearest neighbor within radius + group.
// B=2, N=4096, C=64 fixed by the problem.
// Select uses a per-thread LDS scoreboard indexed by octant code (1 update
// per pair instead of 8 register-scoreboard updates) with a packed unsigned
// monotone key:  ikey = float_bits(dist) - (float_bits(1e-10f)+1)
//   - dist <= 1e-10 (incl. self dist=0) wraps to huge  -> loses
//   - dist >= judge  -> ikey >= seedkey                -> loses (strict <)
//   - valid dists map monotonically into [0, 2^28)     -> plain u32 min
#define BB 2
#define NN 4096
#define CC 64
#define QPB 16              // queries per block
#define TPQ 16              // threads per query (one candidate stripe each)
#define NT (QPB * TPQ)      // 256 threads per block
#define EIGHTHS 8
#define NPE (NN / EIGHTHS)  // 512 candidates per select block

// flat output layout (all float32):
//   out0 grouped_xyz   [B,N,8,3]
//   out1 grouped_points[B,N,8,67]
//   out2 idx (as float)[B,N,8]
#define OUT0_OFF 0
#define OUT1_OFF (BB * NN * 8 * 3)               /* 196608 */
#define OUT2_OFF (OUT1_OFF + BB * NN * 8 * 67)   /* 4587520 */

__global__ __launch_bounds__(NT, 6) void pointsift_select(
    const float* __restrict__ xyz, const float* __restrict__ radius_p,
    float* __restrict__ out)
{
    __shared__ float s_xyz4[NPE * 4];   // 8 KiB: this eighth's coords (f4 pad)
    __shared__ uint2 s_sb[8 * NT];      // 16 KiB: (key,idx) per (octant,thread)

    const int tid = threadIdx.x;
    int blk = blockIdx.x;
    const int h = blk & (EIGHTHS - 1);        // candidate eighth
    blk >>= 3;
    const int b = blk >> 8;                   // 256 query-groups per batch
    const int qbase = (blk & 255) * QPB;

    const float* srcb = xyz + (size_t)b * NN * 3;
    // stage this eighth's candidates into LDS, padded to float4 stride
    {
        const float* src = srcb + (size_t)h * NPE * 3;
        #pragma unroll
        for (int p = tid; p < NPE; p += NT) {
            float4* d = (float4*)(s_xyz4 + p * 4);
            *d = make_float4(src[p * 3 + 0], src[p * 3 + 1], src[p * 3 + 2], 0.0f);
        }
    }

    const float r = radius_p[0];
    const float judge = __fmul_rn(r, r);
    const unsigned OFFC = __float_as_uint(1e-10f) + 1u;   // wrap offset
    const unsigned seedkey = __float_as_uint(judge) - OFFC;

    const int n = qbase + (tid >> 4);         // query index within batch
    const int sub = tid & (TPQ - 1);          // candidate stripe id

    // seed own 8 columns with the diagonal entry (judge, n); duplicates across
    // eighths merge cleanly (equal key, equal idx)
    uint2* mycol = s_sb + tid;
    #pragma unroll
    for (int o = 0; o < 8; ++o) mycol[o * NT] = make_uint2(seedkey, (unsigned)n);

    // query coords from global (query may live in any eighth); L2-hot
    const float qx = srcb[n * 3 + 0];
    const float qy = srcb[n * 3 + 1];
    const float qz = srcb[n * 3 + 2];

    __syncthreads();

    const float4* sx4 = (const float4*)s_xyz4;
    int pg = h * NPE + sub;                   // global candidate index
    #pragma unroll 4
    for (int p = sub; p < NPE; p += TPQ, pg += TPQ) {
        float4 c = sx4[p];
        // diff = candidate - query, fp32, no contraction (must match numpy ref)
        float dx = __fsub_rn(c.x, qx);
        float dy = __fsub_rn(c.y, qy);
        float dz = __fsub_rn(c.z, qz);
        float dist = __fadd_rn(__fadd_rn(__fmul_rn(dx, dx), __fmul_rn(dy, dy)),
                               __fmul_rn(dz, dz));
        // monotone packed key: invalid (self / >=judge) lose automatically
        unsigned ikey = __float_as_uint(dist) - OFFC;
        // octant code = trunc(d+1.0f) dot [4,2,1]; &7 folds the d~1.0 boundary
        // cases (bit=2 -> dist~1 >> judge) into a column where they lose
        int code = ((((int)__fadd_rn(dx, 1.0f)) * 4 +
                     ((int)__fadd_rn(dy, 1.0f)) * 2 +
                     ((int)__fadd_rn(dz, 1.0f))) & 7);
        // branchless RMW on own column: first-min kept (strict <, ascending p)
        uint2* col = s_sb + code * NT + tid;
        uint2 old = *col;                      // ds_read_b64
        bool m = ikey < old.x;
        uint2 nw;
        nw.x = m ? ikey : old.x;
        nw.y = m ? (unsigned)pg : old.y;
        *col = nw;                             // ds_write_b64
    }

    // read back own columns (no barrier: private columns, in-order LDS pipe)
    unsigned bk[8], bi[8];
    #pragma unroll
    for (int o = 0; o < 8; ++o) {
        uint2 v = mycol[o * NT];
        bk[o] = v.x; bi[o] = v.y;
    }

    // butterfly reduce over the 16 stripe-threads of this query
    // (lanes are 16-aligned within the wave); tie-break: smaller index wins
    #pragma unroll
    for (int mm = 1; mm < TPQ; mm <<= 1) {
        #pragma unroll
        for (int o = 0; o < 8; ++o) {
            unsigned ok = (unsigned)__shfl_xor((int)bk[o], mm, 64);
            unsigned oi = (unsigned)__shfl_xor((int)bi[o], mm, 64);
            if (ok < bk[o] || (ok == bk[o] && oi < bi[o])) {
                bk[o] = ok; bi[o] = oi;
            }
        }
    }

    // stripe-leader writes this eighth's 8 partial (key, idx) pairs into the
    // out1 scratch area: tuple t=(b*N+n)*8+o gets floats t*67+2h, t*67+2h+1
    if (sub == 0) {
        const size_t tb = ((size_t)b * NN + n) * 8;
        #pragma unroll
        for (int o = 0; o < 8; ++o) {
            size_t base = OUT1_OFF + (tb + o) * 67 + 2 * h;
            out[base + 0] = __uint_as_float(bk[o]);   // key as raw bits
            out[base + 1] = (float)bi[o];             // idx < 4096: exact
        }
    }
}

// merge the 8 eighth-partials per tuple -> out2 (selected idx, as float)
__global__ __launch_bounds__(256) void pointsift_merge(float* __restrict__ out)
{
    const int t = blockIdx.x * 256 + threadIdx.x;   // tuple id
    const float* part = out + OUT1_OFF + (size_t)t * 67;
    unsigned bk = __float_as_uint(part[0]);
    int bi = (int)part[1];
    #pragma unroll
    for (int h = 1; h < EIGHTHS; ++h) {
        unsigned k = __float_as_uint(part[2 * h]);
        int i = (int)part[2 * h + 1];
        if (k < bk || (k == bk && i < bi)) { bk = k; bi = i; }
    }
    out[OUT2_OFF + t] = (float)bi;
}

// one thread per output element: item = tuple*70 + j
//   j in [0,67): out1[t*67+j]  (j<3: grouped_xyz channel, else feature j-3)
//   j in [67,70): out0[t*3 + (j-67)]
__global__ __launch_bounds__(256) void pointsift_gather(
    const float* __restrict__ xyz, const float* __restrict__ points,
    float* __restrict__ out)
{
    const unsigned item = blockIdx.x * 256u + threadIdx.x;   // grid is exact
    const unsigned t = item / 70u;
    const unsigned j = item - t * 70u;
    const unsigned bn = t >> 3;               // b*N + n
    const unsigned b = bn >> 12;
    const unsigned n = bn & (NN - 1);
    const int i = (int)out[OUT2_OFF + t];     // merged idx (broadcast read)
    const float* xb = xyz + (size_t)b * NN * 3;
    if (j < 67u) {
        float v;
        if (j < 3u) v = __fsub_rn(xb[i * 3 + j], xb[n * 3 + j]);
        else        v = points[((size_t)b * NN + i) * CC + (j - 3u)];
        out[OUT1_OFF + (size_t)t * 67 + j] = v;
    } else {
        const unsigned c = j - 67u;
        out[OUT0_OFF + (size_t)t * 3 + c] =
            __fsub_rn(xb[i * 3 + c], xb[n * 3 + c]);
    }
}

extern "C" void kernel_launch(void* const* d_in, const int* in_sizes, int n_in,
                              void* d_out, int out_size, void* d_ws, size_t ws_size,
                              hipStream_t stream) {
    const float* xyz    = (const float*)d_in[0];
    const float* points = (const float*)d_in[1];
    const float* radius = (const float*)d_in[2];
    float* out = (float*)d_out;

    // A: partial octant select per candidate-eighth (4096 blocks)
    hipLaunchKernelGGL(pointsift_select,
                       dim3(BB * (NN / QPB) * EIGHTHS), dim3(NT), 0, stream,
                       xyz, radius, out);
    // B: merge partials -> out2 (16384 tuples / 256 = 64 blocks)
    hipLaunchKernelGGL(pointsift_merge,
                       dim3(BB * NN * 8 / 256), dim3(256), 0, stream, out);
    // C: gather, one thread per element (16384*70/256 = 4480 blocks, exact)
    hipLaunchKernelGGL(pointsift_gather,
                       dim3(BB * NN * 8 * 70 / 256), dim3(256), 0, stream,
                       xyz, points, out);
}

// Round 7
// 113.693 us; speedup vs baseline: 1.2932x; 1.0324x over previous
//
#include <hip/hip_runtime.h>

// PointSIFT: octant-wise nearest neighbor within radius + group.
// B=2, N=4096, C=64 fixed by the problem.
// Select: per-thread LDS scoreboard indexed by octant code, updated with a
// single fire-and-forget ds_min_u64 (atomicMin on a private column).
// Packed key: hi = float_bits(dist) - (float_bits(1e-10f)+1), lo = idx.
//   - dist <= 1e-10 (incl. self dist=0) wraps hi to huge   -> loses
//   - dist >= judge forced to 0xFFFFFFFF (strict-< exact)  -> loses
//   - valid dists map monotonically; u64 min ties on key fall to min idx,
//     which IS the reference's first-min tie-break.
#define BB 2
#define NN 4096
#define CC 64
#define QPB 16              // queries per block
#define TPQ 16              // threads per query (one candidate stripe each)
#define NT (QPB * TPQ)      // 256 threads per block
#define EIGHTHS 8
#define NPE (NN / EIGHTHS)  // 512 candidates per select block

// flat output layout (all float32):
//   out0 grouped_xyz   [B,N,8,3]
//   out1 grouped_points[B,N,8,67]
//   out2 idx (as float)[B,N,8]
#define OUT0_OFF 0
#define OUT1_OFF (BB * NN * 8 * 3)               /* 196608 */
#define OUT2_OFF (OUT1_OFF + BB * NN * 8 * 67)   /* 4587520 */

__global__ __launch_bounds__(NT, 6) void pointsift_select(
    const float* __restrict__ xyz, const float* __restrict__ radius_p,
    float* __restrict__ out)
{
    __shared__ float s_xyz4[NPE * 4];               // 8 KiB candidate coords
    __shared__ unsigned long long s_sb[8 * NT];     // 16 KiB (key<<32|idx)

    const int tid = threadIdx.x;
    int blk = blockIdx.x;
    const int h = blk & (EIGHTHS - 1);        // candidate eighth
    blk >>= 3;
    const int b = blk >> 8;                   // 256 query-groups per batch
    const int qbase = (blk & 255) * QPB;

    const float* srcb = xyz + (size_t)b * NN * 3;
    // stage this eighth's candidates into LDS, padded to float4 stride
    {
        const float* src = srcb + (size_t)h * NPE * 3;
        #pragma unroll
        for (int p = tid; p < NPE; p += NT) {
            float4* d = (float4*)(s_xyz4 + p * 4);
            *d = make_float4(src[p * 3 + 0], src[p * 3 + 1], src[p * 3 + 2], 0.0f);
        }
    }

    const float r = radius_p[0];
    const float judge = __fmul_rn(r, r);
    const unsigned OFFC = __float_as_uint(1e-10f) + 1u;   // wrap offset
    const unsigned seedkey = __float_as_uint(judge) - OFFC;

    const int n = qbase + (tid >> 4);         // query index within batch
    const int sub = tid & (TPQ - 1);          // candidate stripe id

    // seed own 8 columns with the diagonal entry (judge, n); duplicates
    // across eighths merge cleanly (equal key, equal idx)
    const unsigned long long seed64 =
        ((unsigned long long)seedkey << 32) | (unsigned)n;
    unsigned long long* mycol = s_sb + tid;
    #pragma unroll
    for (int o = 0; o < 8; ++o) mycol[o * NT] = seed64;

    // query coords from global (query may live in any eighth); L2-hot
    const float qx = srcb[n * 3 + 0];
    const float qy = srcb[n * 3 + 1];
    const float qz = srcb[n * 3 + 2];

    __syncthreads();

    const float4* sx4 = (const float4*)s_xyz4;
    int pg = h * NPE + sub;                   // global candidate index
    #pragma unroll 4
    for (int p = sub; p < NPE; p += TPQ, pg += TPQ) {
        float4 c = sx4[p];
        // diff = candidate - query, fp32, no contraction (must match numpy ref)
        float dx = __fsub_rn(c.x, qx);
        float dy = __fsub_rn(c.y, qy);
        float dz = __fsub_rn(c.z, qz);
        float dist = __fadd_rn(__fadd_rn(__fmul_rn(dx, dx), __fmul_rn(dy, dy)),
                               __fmul_rn(dz, dz));
        // monotone packed key; low end (self/too-close) wraps via OFFC, high
        // end (dist >= judge) forced to lose so strict-< semantics are exact
        unsigned ikey = __float_as_uint(dist) - OFFC;
        ikey = (dist >= judge) ? 0xFFFFFFFFu : ikey;
        // octant code = trunc(d+1.0f) dot [4,2,1]; &7 folds the d~1.0
        // boundary (bit=2, dist~1 >> judge) into a column where it loses
        int code = ((((int)__fadd_rn(dx, 1.0f)) * 4 +
                     ((int)__fadd_rn(dy, 1.0f)) * 2 +
                     ((int)__fadd_rn(dz, 1.0f))) & 7);
        // fire-and-forget: ds_min_u64 on own column, no VALU, no dependency
        atomicMin(&s_sb[code * NT + tid],
                  ((unsigned long long)ikey << 32) | (unsigned)pg);
    }

    // read back own columns (private columns; DS pipe is in-order per wave)
    unsigned long long bv[8];
    #pragma unroll
    for (int o = 0; o < 8; ++o) bv[o] = mycol[o * NT];

    // butterfly reduce over the 16 stripe-threads of this query
    // (lanes are 16-aligned within the wave); packed u64 min = first-min
    #pragma unroll
    for (int mm = 1; mm < TPQ; mm <<= 1) {
        #pragma unroll
        for (int o = 0; o < 8; ++o) {
            unsigned long long ov = __shfl_xor(bv[o], mm, 64);
            if (ov < bv[o]) bv[o] = ov;
        }
    }

    // stripe-leader writes this eighth's 8 partial (key, idx) pairs into the
    // out1 scratch area: tuple t=(b*N+n)*8+o gets floats t*67+2h, t*67+2h+1
    if (sub == 0) {
        const size_t tb = ((size_t)b * NN + n) * 8;
        #pragma unroll
        for (int o = 0; o < 8; ++o) {
            size_t base = OUT1_OFF + (tb + o) * 67 + 2 * h;
            out[base + 0] = __uint_as_float((unsigned)(bv[o] >> 32));
            out[base + 1] = (float)(unsigned)(bv[o] & 0xFFFFFFFFu);
        }
    }
}

// merge the 8 eighth-partials per tuple -> out2 (selected idx, as float)
__global__ __launch_bounds__(256) void pointsift_merge(float* __restrict__ out)
{
    const int t = blockIdx.x * 256 + threadIdx.x;   // tuple id
    const float* part = out + OUT1_OFF + (size_t)t * 67;
    unsigned bk = __float_as_uint(part[0]);
    int bi = (int)part[1];
    #pragma unroll
    for (int h = 1; h < EIGHTHS; ++h) {
        unsigned k = __float_as_uint(part[2 * h]);
        int i = (int)part[2 * h + 1];
        if (k < bk || (k == bk && i < bi)) { bk = k; bi = i; }
    }
    out[OUT2_OFF + t] = (float)bi;
}

// one thread per output element: item = tuple*70 + j
//   j in [0,67): out1[t*67+j]  (j<3: grouped_xyz channel, else feature j-3)
//   j in [67,70): out0[t*3 + (j-67)]
__global__ __launch_bounds__(256) void pointsift_gather(
    const float* __restrict__ xyz, const float* __restrict__ points,
    float* __restrict__ out)
{
    const unsigned item = blockIdx.x * 256u + threadIdx.x;   // grid is exact
    const unsigned t = item / 70u;
    const unsigned j = item - t * 70u;
    const unsigned bn = t >> 3;               // b*N + n
    const unsigned b = bn >> 12;
    const unsigned n = bn & (NN - 1);
    const int i = (int)out[OUT2_OFF + t];     // merged idx (broadcast read)
    const float* xb = xyz + (size_t)b * NN * 3;
    if (j < 67u) {
        float v;
        if (j < 3u) v = __fsub_rn(xb[i * 3 + j], xb[n * 3 + j]);
        else        v = points[((size_t)b * NN + i) * CC + (j - 3u)];
        out[OUT1_OFF + (size_t)t * 67 + j] = v;
    } else {
        const unsigned c = j - 67u;
        out[OUT0_OFF + (size_t)t * 3 + c] =
            __fsub_rn(xb[i * 3 + c], xb[n * 3 + c]);
    }
}

extern "C" void kernel_launch(void* const* d_in, const int* in_sizes, int n_in,
                              void* d_out, int out_size, void* d_ws, size_t ws_size,
                              hipStream_t stream) {
    const float* xyz    = (const float*)d_in[0];
    const float* points = (const float*)d_in[1];
    const float* radius = (const float*)d_in[2];
    float* out = (float*)d_out;

    // A: partial octant select per candidate-eighth (4096 blocks)
    hipLaunchKernelGGL(pointsift_select,
                       dim3(BB * (NN / QPB) * EIGHTHS), dim3(NT), 0, stream,
                       xyz, radius, out);
    // B: merge partials -> out2 (16384 tuples / 256 = 64 blocks)
    hipLaunchKernelGGL(pointsift_merge,
                       dim3(BB * NN * 8 / 256), dim3(256), 0, stream, out);
    // C: gather, one thread per element (16384*70/256 = 4480 blocks, exact)
    hipLaunchKernelGGL(pointsift_gather,
                       dim3(BB * NN * 8 * 70 / 256), dim3(256), 0, stream,
                       xyz, points, out);
}